// Round 1
// baseline (857.457 us; speedup 1.0000x reference)
//
#include <hip/hip_runtime.h>
#include <hip/hip_bf16.h>
#include <cstdint>
#include <cstddef>

// QRNN (window=2, zoneout=0) fused: f16 MFMA GEMM for gates + epilogue
// activations + sequential diagonal-recurrence scan.
//
// Shapes: B=16, S=2048, D=1024, H=1024. GEMM: M=S*B=32768, N=3*H=3072, K=2*D=2048.

typedef _Float16 f16;
typedef _Float16 f16x4 __attribute__((ext_vector_type(4)));
typedef _Float16 f16x8 __attribute__((ext_vector_type(8)));
typedef float f32x4 __attribute__((ext_vector_type(4)));

#define Bb 16
#define Ss 2048
#define Dd 1024
#define Hh 1024
#define Nn (3 * Hh)   // 3072
#define Kk (2 * Dd)   // 2048
#define BH (Bb * Hh)  // 16384

__device__ __forceinline__ void gl_lds16(const void* g, void* l) {
  __builtin_amdgcn_global_load_lds(
      (const __attribute__((address_space(1))) void*)g,
      (__attribute__((address_space(3))) void*)l, 16, 0, 0);
}

__global__ void cvt_f32_f16(const float* __restrict__ in, f16* __restrict__ out, int n4) {
  int i = blockIdx.x * blockDim.x + threadIdx.x;
  if (i < n4) {
    const float4 v = ((const float4*)in)[i];
    f16x4 h;
    h[0] = (f16)v.x; h[1] = (f16)v.y; h[2] = (f16)v.z; h[3] = (f16)v.w;
    ((f16x4*)out)[i] = h;
  }
}

// 128x128 tile, BK=64, 256 threads (4 waves, each 64x64 via 4x4 MFMA 16x16x32 f16).
__global__ __launch_bounds__(256, 2)
void gemm_gates(const f16* __restrict__ Xh,    // (B,S,D) f16
                const f16* __restrict__ Wh,    // (3H,2D) f16
                const float* __restrict__ bias,// (3H)
                const f16* __restrict__ zblk,  // >=128 B of zeros
                f16* __restrict__ Zg, f16* __restrict__ Fg, f16* __restrict__ Og) {
  __shared__ __align__(16) f16 As[128 * 64];
  __shared__ __align__(16) f16 Bs[128 * 64];

  const int tid  = threadIdx.x;
  const int wave = tid >> 6;
  const int lane = tid & 63;
  const int bn = blockIdx.x;   // 0..23
  const int bm = blockIdx.y;   // 0..255
  const int m0 = bm * 128;
  const int n0 = bn * 128;

  const int wm = (wave >> 1) * 64;
  const int wn = (wave & 1) * 64;
  const int r  = lane & 15;
  const int q  = lane >> 4;

  // staging: each wave covers rows [wave*32, wave*32+32); per load-instr 8 rows,
  // lane -> row = row0 + lane/8, k-seg = (lane&7)*8 elems (16B). LDS dst is
  // wave-uniform base; HW scatters lane*16 which matches [row][k] layout exactly.
  const int sseg = (lane & 7) * 8;
  const int srl  = lane >> 3;

  int as_[4], ab_[4];
#pragma unroll
  for (int i = 0; i < 4; ++i) {
    int mrow = m0 + wave * 32 + i * 8 + srl;
    as_[i] = mrow >> 4;   // s
    ab_[i] = mrow & 15;   // b
  }

  f32x4 acc[4][4];
#pragma unroll
  for (int i = 0; i < 4; ++i)
#pragma unroll
    for (int j = 0; j < 4; ++j)
      acc[i][j] = {0.f, 0.f, 0.f, 0.f};

  for (int kt = 0; kt < 32; ++kt) {
    const int kf = kt * 64;
    __syncthreads();
    // stage A (gathered window-concat)
#pragma unroll
    for (int i = 0; i < 4; ++i) {
      const int row0 = wave * 32 + i * 8;
      const f16* gp;
      if (kf < 1024) {
        gp = Xh + (size_t)ab_[i] * (Ss * Dd) + as_[i] * Dd + kf + sseg;
      } else if (as_[i] > 0) {
        gp = Xh + (size_t)ab_[i] * (Ss * Dd) + (as_[i] - 1) * Dd + (kf - 1024) + sseg;
      } else {
        gp = zblk + sseg;
      }
      gl_lds16(gp, &As[row0 * 64]);
    }
    // stage B (weights, [n][k] row-major = B^T natural layout)
#pragma unroll
    for (int i = 0; i < 4; ++i) {
      const int row0 = wave * 32 + i * 8;
      const f16* gp = Wh + (size_t)(n0 + row0 + srl) * Kk + kf + sseg;
      gl_lds16(gp, &Bs[row0 * 64]);
    }
    __syncthreads();
#pragma unroll
    for (int kk = 0; kk < 64; kk += 32) {
      f16x8 af[4], bf[4];
#pragma unroll
      for (int mi = 0; mi < 4; ++mi)
        af[mi] = *(const f16x8*)&As[(wm + mi * 16 + r) * 64 + kk + q * 8];
#pragma unroll
      for (int ni = 0; ni < 4; ++ni)
        bf[ni] = *(const f16x8*)&Bs[(wn + ni * 16 + r) * 64 + kk + q * 8];
#pragma unroll
      for (int mi = 0; mi < 4; ++mi)
#pragma unroll
        for (int ni = 0; ni < 4; ++ni)
          acc[mi][ni] =
              __builtin_amdgcn_mfma_f32_16x16x32_f16(af[mi], bf[ni], acc[mi][ni], 0, 0, 0);
    }
  }

  // epilogue: C/D layout col=lane&15, row=q*4+reg. Gate uniform per block
  // (n0 is 128-aligned, gate regions 1024-aligned).
  const int gate = n0 >> 10;
  f16* gp_out = (gate == 0) ? Zg : ((gate == 1) ? Fg : Og);
#pragma unroll
  for (int ni = 0; ni < 4; ++ni) {
    const int gcol = n0 + wn + ni * 16 + r;
    const int h = gcol & 1023;
    const float bv = bias[gcol];
#pragma unroll
    for (int mi = 0; mi < 4; ++mi) {
#pragma unroll
      for (int reg = 0; reg < 4; ++reg) {
        const int grow = m0 + wm + mi * 16 + q * 4 + reg;
        const int s = grow >> 4, bb = grow & 15;
        const float y = acc[mi][ni][reg] + bv;
        float v;
        if (gate == 0) v = 2.f / (1.f + __expf(-2.f * y)) - 1.f;  // tanh
        else           v = 1.f / (1.f + __expf(-y));              // sigmoid
        gp_out[(size_t)s * BH + bb * Hh + h] = (f16)v;
      }
    }
  }
}

// One thread per (b,h) chain; 256 blocks x 64 threads = 1 wave on every CU.
// U=32 double-buffered register prefetch to hide HBM latency.
__global__ __launch_bounds__(64, 1)
void scan_fused(const f16* __restrict__ Zg, const f16* __restrict__ Fg,
                const f16* __restrict__ Og, const float* __restrict__ hidden,
                float* __restrict__ out) {
  const int g = blockIdx.x * 64 + threadIdx.x;  // 0..16383
  float c = hidden[g];

  constexpr int U = 32;
  f16 z0[U], f0[U], o0[U], z1[U], f1[U], o1[U];

#pragma unroll
  for (int i = 0; i < U; ++i) {
    z0[i] = Zg[(size_t)i * BH + g];
    f0[i] = Fg[(size_t)i * BH + g];
    o0[i] = Og[(size_t)i * BH + g];
  }

  for (int t = 0; t < Ss; t += 2 * U) {
    if (t + U < Ss) {
#pragma unroll
      for (int i = 0; i < U; ++i) {
        z1[i] = Zg[(size_t)(t + U + i) * BH + g];
        f1[i] = Fg[(size_t)(t + U + i) * BH + g];
        o1[i] = Og[(size_t)(t + U + i) * BH + g];
      }
    }
#pragma unroll
    for (int i = 0; i < U; ++i) {
      const float z = (float)z0[i], f = (float)f0[i], o = (float)o0[i];
      c = fmaf(f, z - c, c);                       // c = f*z + (1-f)*c
      out[(size_t)(t + i) * BH + g] = o * c;
    }
    if (t + 2 * U < Ss) {
#pragma unroll
      for (int i = 0; i < U; ++i) {
        z0[i] = Zg[(size_t)(t + 2 * U + i) * BH + g];
        f0[i] = Fg[(size_t)(t + 2 * U + i) * BH + g];
        o0[i] = Og[(size_t)(t + 2 * U + i) * BH + g];
      }
    }
#pragma unroll
    for (int i = 0; i < U; ++i) {
      const float z = (float)z1[i], f = (float)f1[i], o = (float)o1[i];
      c = fmaf(f, z - c, c);
      out[(size_t)(t + U + i) * BH + g] = o * c;
    }
  }
  out[(size_t)Ss * BH + g] = c;  // c_last
}

extern "C" void kernel_launch(void* const* d_in, const int* in_sizes, int n_in,
                              void* d_out, int out_size, void* d_ws, size_t ws_size,
                              hipStream_t stream) {
  const float* X      = (const float*)d_in[0];  // (B,S,D)
  const float* hidden = (const float*)d_in[1];  // (B,H)
  const float* W      = (const float*)d_in[2];  // (3H,2D)
  const float* bias   = (const float*)d_in[3];  // (3H)
  float* out = (float*)d_out;

  // ws layout (all offsets 256B-aligned):
  //   [0,256)        zero block for s==0 shifted reads
  //   Wh  f16        3072*2048*2  = 12,582,912 B
  //   Xh  f16        16*2048*1024*2 = 67,108,864 B
  //   Zg/Fg/Og f16   67,108,864 B each
  // total ~281 MB
  char* ws = (char*)d_ws;
  f16* zblk = (f16*)ws;
  f16* Wh = (f16*)(ws + 256);
  f16* Xh = (f16*)(ws + 256 + 12582912);
  f16* Zg = (f16*)(ws + 256 + 12582912 + 67108864);
  f16* Fg = (f16*)(ws + 256 + 12582912 + 2 * 67108864);
  f16* Og = (f16*)(ws + 256 + 12582912 + 3 * 67108864);

  hipMemsetAsync(zblk, 0, 256, stream);

  {
    int n4 = (Nn * Kk) / 4;
    cvt_f32_f16<<<(n4 + 255) / 256, 256, 0, stream>>>(W, Wh, n4);
  }
  {
    int n4 = (Bb * Ss * Dd) / 4;
    cvt_f32_f16<<<(n4 + 255) / 256, 256, 0, stream>>>(X, Xh, n4);
  }
  gemm_gates<<<dim3(24, 256), 256, 0, stream>>>(Xh, Wh, bias, zblk, Zg, Fg, Og);
  scan_fused<<<256, 64, 0, stream>>>(Zg, Fg, Og, hidden, out);
}

// Round 2
// 783.719 us; speedup vs baseline: 1.0941x; 1.0941x over previous
//
#include <hip/hip_runtime.h>
#include <hip/hip_bf16.h>
#include <cstdint>
#include <cstddef>

// QRNN (window=2) fused: f16 MFMA GEMM for gates + epilogue activations +
// sequential diagonal-recurrence scan.
//
// R1: XOR-swizzled LDS layout to kill the 16-way bank conflicts
// (SQ_LDS_BANK_CONFLICT was 1.5e8 = ~40% of GEMM cycles). Swizzle is applied
// on the *gather* side of global_load_lds (lane->segment permutation), since
// the LDS destination is hardware-fixed at base + lane*16.
// Also __launch_bounds__(256,2) -> (256,4): 80 VGPRs / 32KB LDS allow 4 blocks/CU.

typedef _Float16 f16;
typedef _Float16 f16x4 __attribute__((ext_vector_type(4)));
typedef _Float16 f16x8 __attribute__((ext_vector_type(8)));
typedef float f32x4 __attribute__((ext_vector_type(4)));

#define Bb 16
#define Ss 2048
#define Dd 1024
#define Hh 1024
#define Nn (3 * Hh)   // 3072
#define Kk (2 * Dd)   // 2048
#define BH (Bb * Hh)  // 16384

__device__ __forceinline__ void gl_lds16(const void* g, void* l) {
  __builtin_amdgcn_global_load_lds(
      (const __attribute__((address_space(1))) void*)g,
      (__attribute__((address_space(3))) void*)l, 16, 0, 0);
}

__global__ void cvt_f32_f16(const float* __restrict__ in, f16* __restrict__ out, int n4) {
  int i = blockIdx.x * blockDim.x + threadIdx.x;
  if (i < n4) {
    const float4 v = ((const float4*)in)[i];
    f16x4 h;
    h[0] = (f16)v.x; h[1] = (f16)v.y; h[2] = (f16)v.z; h[3] = (f16)v.w;
    ((f16x4*)out)[i] = h;
  }
}

// 128x128 tile, BK=64, 256 threads (4 waves, each 64x64 via 4x4 MFMA 16x16x32 f16).
__global__ __launch_bounds__(256, 4)
void gemm_gates(const f16* __restrict__ Xh,    // (B,S,D) f16
                const f16* __restrict__ Wh,    // (3H,2D) f16
                const float* __restrict__ bias,// (3H)
                const f16* __restrict__ zblk,  // >=256 B of zeros
                f16* __restrict__ Zg, f16* __restrict__ Fg, f16* __restrict__ Og) {
  __shared__ __align__(16) f16 As[128 * 64];
  __shared__ __align__(16) f16 Bs[128 * 64];

  const int tid  = threadIdx.x;
  const int wave = tid >> 6;
  const int lane = tid & 63;
  const int bn = blockIdx.x;   // 0..23
  const int bm = blockIdx.y;   // 0..255
  const int m0 = bm * 128;
  const int n0 = bn * 128;

  const int wm = (wave >> 1) * 64;
  const int wn = (wave & 1) * 64;
  const int r  = lane & 15;
  const int q  = lane >> 4;

  // Staging: per instr 8 rows x 64 k-elems. lane -> row = row0 + lane/8.
  // XOR swizzle: LDS position p (= lane&7) holds global segment p ^ (row&7);
  // row bases are 8-aligned so row&7 == lane>>3.
  const int srl  = lane >> 3;                    // row within 8-row group = row&7
  const int sseg = ((lane & 7) ^ srl) * 8;       // swizzled global k-offset (elems)

  int as_[4], ab_[4];
#pragma unroll
  for (int i = 0; i < 4; ++i) {
    int mrow = m0 + wave * 32 + i * 8 + srl;
    as_[i] = mrow >> 4;   // s
    ab_[i] = mrow & 15;   // b
  }

  f32x4 acc[4][4];
#pragma unroll
  for (int i = 0; i < 4; ++i)
#pragma unroll
    for (int j = 0; j < 4; ++j)
      acc[i][j] = {0.f, 0.f, 0.f, 0.f};

  for (int kt = 0; kt < 32; ++kt) {
    const int kf = kt * 64;
    __syncthreads();
    // stage A (gathered window-concat); sseg < 64 keeps each load within the
    // same 64-elem k-tile, so the kf-level branch stays valid under swizzle.
#pragma unroll
    for (int i = 0; i < 4; ++i) {
      const int row0 = wave * 32 + i * 8;
      const f16* gp;
      if (kf < 1024) {
        gp = Xh + (size_t)ab_[i] * (Ss * Dd) + as_[i] * Dd + kf + sseg;
      } else if (as_[i] > 0) {
        gp = Xh + (size_t)ab_[i] * (Ss * Dd) + (as_[i] - 1) * Dd + (kf - 1024) + sseg;
      } else {
        gp = zblk + sseg;
      }
      gl_lds16(gp, &As[row0 * 64]);
    }
    // stage B (weights, [n][k] row-major = B^T natural layout)
#pragma unroll
    for (int i = 0; i < 4; ++i) {
      const int row0 = wave * 32 + i * 8;
      const f16* gp = Wh + (size_t)(n0 + row0 + srl) * Kk + kf + sseg;
      gl_lds16(gp, &Bs[row0 * 64]);
    }
    __syncthreads();
#pragma unroll
    for (int kk = 0; kk < 64; kk += 32) {
      f16x8 af[4], bf[4];
#pragma unroll
      for (int mi = 0; mi < 4; ++mi) {
        const int row = wm + mi * 16 + r;
        const int seg = ((kk >> 3) + q) ^ (row & 7);
        af[mi] = *(const f16x8*)&As[row * 64 + seg * 8];
      }
#pragma unroll
      for (int ni = 0; ni < 4; ++ni) {
        const int row = wn + ni * 16 + r;
        const int seg = ((kk >> 3) + q) ^ (row & 7);
        bf[ni] = *(const f16x8*)&Bs[row * 64 + seg * 8];
      }
#pragma unroll
      for (int mi = 0; mi < 4; ++mi)
#pragma unroll
        for (int ni = 0; ni < 4; ++ni)
          acc[mi][ni] =
              __builtin_amdgcn_mfma_f32_16x16x32_f16(af[mi], bf[ni], acc[mi][ni], 0, 0, 0);
    }
  }

  // epilogue: C/D layout col=lane&15, row=q*4+reg. Gate uniform per block
  // (n0 is 128-aligned, gate regions 1024-aligned).
  const int gate = n0 >> 10;
  f16* gp_out = (gate == 0) ? Zg : ((gate == 1) ? Fg : Og);
#pragma unroll
  for (int ni = 0; ni < 4; ++ni) {
    const int gcol = n0 + wn + ni * 16 + r;
    const int h = gcol & 1023;
    const float bv = bias[gcol];
#pragma unroll
    for (int mi = 0; mi < 4; ++mi) {
#pragma unroll
      for (int reg = 0; reg < 4; ++reg) {
        const int grow = m0 + wm + mi * 16 + q * 4 + reg;
        const int s = grow >> 4, bb = grow & 15;
        const float y = acc[mi][ni][reg] + bv;
        float v;
        if (gate == 0) v = 2.f / (1.f + __expf(-2.f * y)) - 1.f;  // tanh
        else           v = 1.f / (1.f + __expf(-y));              // sigmoid
        gp_out[(size_t)s * BH + bb * Hh + h] = (f16)v;
      }
    }
  }
}

// One thread per (b,h) chain; 256 blocks x 64 threads = 1 wave on every CU.
// U=32 double-buffered register prefetch to hide HBM latency.
__global__ __launch_bounds__(64, 1)
void scan_fused(const f16* __restrict__ Zg, const f16* __restrict__ Fg,
                const f16* __restrict__ Og, const float* __restrict__ hidden,
                float* __restrict__ out) {
  const int g = blockIdx.x * 64 + threadIdx.x;  // 0..16383
  float c = hidden[g];

  constexpr int U = 32;
  f16 z0[U], f0[U], o0[U], z1[U], f1[U], o1[U];

#pragma unroll
  for (int i = 0; i < U; ++i) {
    z0[i] = Zg[(size_t)i * BH + g];
    f0[i] = Fg[(size_t)i * BH + g];
    o0[i] = Og[(size_t)i * BH + g];
  }

  for (int t = 0; t < Ss; t += 2 * U) {
    if (t + U < Ss) {
#pragma unroll
      for (int i = 0; i < U; ++i) {
        z1[i] = Zg[(size_t)(t + U + i) * BH + g];
        f1[i] = Fg[(size_t)(t + U + i) * BH + g];
        o1[i] = Og[(size_t)(t + U + i) * BH + g];
      }
    }
#pragma unroll
    for (int i = 0; i < U; ++i) {
      const float z = (float)z0[i], f = (float)f0[i], o = (float)o0[i];
      c = fmaf(f, z - c, c);                       // c = f*z + (1-f)*c
      out[(size_t)(t + i) * BH + g] = o * c;
    }
    if (t + 2 * U < Ss) {
#pragma unroll
      for (int i = 0; i < U; ++i) {
        z0[i] = Zg[(size_t)(t + 2 * U + i) * BH + g];
        f0[i] = Fg[(size_t)(t + 2 * U + i) * BH + g];
        o0[i] = Og[(size_t)(t + 2 * U + i) * BH + g];
      }
    }
#pragma unroll
    for (int i = 0; i < U; ++i) {
      const float z = (float)z1[i], f = (float)f1[i], o = (float)o1[i];
      c = fmaf(f, z - c, c);
      out[(size_t)(t + U + i) * BH + g] = o * c;
    }
  }
  out[(size_t)Ss * BH + g] = c;  // c_last
}

extern "C" void kernel_launch(void* const* d_in, const int* in_sizes, int n_in,
                              void* d_out, int out_size, void* d_ws, size_t ws_size,
                              hipStream_t stream) {
  const float* X      = (const float*)d_in[0];  // (B,S,D)
  const float* hidden = (const float*)d_in[1];  // (B,H)
  const float* W      = (const float*)d_in[2];  // (3H,2D)
  const float* bias   = (const float*)d_in[3];  // (3H)
  float* out = (float*)d_out;

  // ws layout (all offsets 256B-aligned):
  //   [0,256)        zero block for s==0 shifted reads
  //   Wh  f16        3072*2048*2  = 12,582,912 B
  //   Xh  f16        16*2048*1024*2 = 67,108,864 B
  //   Zg/Fg/Og f16   67,108,864 B each
  // total ~281 MB
  char* ws = (char*)d_ws;
  f16* zblk = (f16*)ws;
  f16* Wh = (f16*)(ws + 256);
  f16* Xh = (f16*)(ws + 256 + 12582912);
  f16* Zg = (f16*)(ws + 256 + 12582912 + 67108864);
  f16* Fg = (f16*)(ws + 256 + 12582912 + 2 * 67108864);
  f16* Og = (f16*)(ws + 256 + 12582912 + 3 * 67108864);

  hipMemsetAsync(zblk, 0, 256, stream);

  {
    int n4 = (Nn * Kk) / 4;
    cvt_f32_f16<<<(n4 + 255) / 256, 256, 0, stream>>>(W, Wh, n4);
  }
  {
    int n4 = (Bb * Ss * Dd) / 4;
    cvt_f32_f16<<<(n4 + 255) / 256, 256, 0, stream>>>(X, Xh, n4);
  }
  gemm_gates<<<dim3(24, 256), 256, 0, stream>>>(Xh, Wh, bias, zblk, Zg, Fg, Og);
  scan_fused<<<256, 64, 0, stream>>>(Zg, Fg, Og, hidden, out);
}

// Round 3
// 735.555 us; speedup vs baseline: 1.1657x; 1.0655x over previous
//
#include <hip/hip_runtime.h>
#include <hip/hip_bf16.h>
#include <cstdint>
#include <cstddef>

// QRNN (window=2) fused: f16 MFMA GEMM for gates + epilogue activations +
// sequence-parallel diagonal-recurrence scan.
//
// R1: XOR-swizzled LDS (SQ_LDS_BANK_CONFLICT 1.5e8 -> 0), launch_bounds(256,4).
//     GEMM 605 -> 440 us (937 TF, m97-structure plateau).
// R2: scan was ~290 us at ~1.1 TB/s (1 wave/CU = parallelism-starved).
//     Replaced with 3-phase sequence-parallel scan: c_out = A*c_in + B per
//     128-step chunk (A = prod(1-f), B = chunk scan from 0), 16 chunks x
//     8192 chain-pairs = 8 waves/CU, f16x2 loads (2 chains/thread).

typedef _Float16 f16;
typedef _Float16 f16x2 __attribute__((ext_vector_type(2)));
typedef _Float16 f16x4 __attribute__((ext_vector_type(4)));
typedef _Float16 f16x8 __attribute__((ext_vector_type(8)));
typedef float f32x4 __attribute__((ext_vector_type(4)));

#define Bb 16
#define Ss 2048
#define Dd 1024
#define Hh 1024
#define Nn (3 * Hh)   // 3072
#define Kk (2 * Dd)   // 2048
#define BH (Bb * Hh)  // 16384
#define NCH 16        // scan chunks
#define CL 128        // chunk length = Ss/NCH
#define NQ 8192       // chain pairs = BH/2

__device__ __forceinline__ void gl_lds16(const void* g, void* l) {
  __builtin_amdgcn_global_load_lds(
      (const __attribute__((address_space(1))) void*)g,
      (__attribute__((address_space(3))) void*)l, 16, 0, 0);
}

__global__ void cvt_f32_f16(const float* __restrict__ in, f16* __restrict__ out, int n4) {
  int i = blockIdx.x * blockDim.x + threadIdx.x;
  if (i < n4) {
    const float4 v = ((const float4*)in)[i];
    f16x4 h;
    h[0] = (f16)v.x; h[1] = (f16)v.y; h[2] = (f16)v.z; h[3] = (f16)v.w;
    ((f16x4*)out)[i] = h;
  }
}

// 128x128 tile, BK=64, 256 threads (4 waves, each 64x64 via 4x4 MFMA 16x16x32 f16).
__global__ __launch_bounds__(256, 4)
void gemm_gates(const f16* __restrict__ Xh,    // (B,S,D) f16
                const f16* __restrict__ Wh,    // (3H,2D) f16
                const float* __restrict__ bias,// (3H)
                const f16* __restrict__ zblk,  // >=256 B of zeros
                f16* __restrict__ Zg, f16* __restrict__ Fg, f16* __restrict__ Og) {
  __shared__ __align__(16) f16 As[128 * 64];
  __shared__ __align__(16) f16 Bs[128 * 64];

  const int tid  = threadIdx.x;
  const int wave = tid >> 6;
  const int lane = tid & 63;
  const int bn = blockIdx.x;   // 0..23
  const int bm = blockIdx.y;   // 0..255
  const int m0 = bm * 128;
  const int n0 = bn * 128;

  const int wm = (wave >> 1) * 64;
  const int wn = (wave & 1) * 64;
  const int r  = lane & 15;
  const int q  = lane >> 4;

  // Staging: per instr 8 rows x 64 k-elems. lane -> row = row0 + lane/8.
  // XOR swizzle: LDS position p (= lane&7) holds global segment p ^ (row&7);
  // row bases are 8-aligned so row&7 == lane>>3.
  const int srl  = lane >> 3;                    // row within 8-row group = row&7
  const int sseg = ((lane & 7) ^ srl) * 8;       // swizzled global k-offset (elems)

  int as_[4], ab_[4];
#pragma unroll
  for (int i = 0; i < 4; ++i) {
    int mrow = m0 + wave * 32 + i * 8 + srl;
    as_[i] = mrow >> 4;   // s
    ab_[i] = mrow & 15;   // b
  }

  f32x4 acc[4][4];
#pragma unroll
  for (int i = 0; i < 4; ++i)
#pragma unroll
    for (int j = 0; j < 4; ++j)
      acc[i][j] = {0.f, 0.f, 0.f, 0.f};

  for (int kt = 0; kt < 32; ++kt) {
    const int kf = kt * 64;
    __syncthreads();
    // stage A (gathered window-concat); sseg < 64 keeps each load within the
    // same 64-elem k-tile, so the kf-level branch stays valid under swizzle.
#pragma unroll
    for (int i = 0; i < 4; ++i) {
      const int row0 = wave * 32 + i * 8;
      const f16* gp;
      if (kf < 1024) {
        gp = Xh + (size_t)ab_[i] * (Ss * Dd) + as_[i] * Dd + kf + sseg;
      } else if (as_[i] > 0) {
        gp = Xh + (size_t)ab_[i] * (Ss * Dd) + (as_[i] - 1) * Dd + (kf - 1024) + sseg;
      } else {
        gp = zblk + sseg;
      }
      gl_lds16(gp, &As[row0 * 64]);
    }
    // stage B (weights, [n][k] row-major = B^T natural layout)
#pragma unroll
    for (int i = 0; i < 4; ++i) {
      const int row0 = wave * 32 + i * 8;
      const f16* gp = Wh + (size_t)(n0 + row0 + srl) * Kk + kf + sseg;
      gl_lds16(gp, &Bs[row0 * 64]);
    }
    __syncthreads();
#pragma unroll
    for (int kk = 0; kk < 64; kk += 32) {
      f16x8 af[4], bf[4];
#pragma unroll
      for (int mi = 0; mi < 4; ++mi) {
        const int row = wm + mi * 16 + r;
        const int seg = ((kk >> 3) + q) ^ (row & 7);
        af[mi] = *(const f16x8*)&As[row * 64 + seg * 8];
      }
#pragma unroll
      for (int ni = 0; ni < 4; ++ni) {
        const int row = wn + ni * 16 + r;
        const int seg = ((kk >> 3) + q) ^ (row & 7);
        bf[ni] = *(const f16x8*)&Bs[row * 64 + seg * 8];
      }
#pragma unroll
      for (int mi = 0; mi < 4; ++mi)
#pragma unroll
        for (int ni = 0; ni < 4; ++ni)
          acc[mi][ni] =
              __builtin_amdgcn_mfma_f32_16x16x32_f16(af[mi], bf[ni], acc[mi][ni], 0, 0, 0);
    }
  }

  // epilogue: C/D layout col=lane&15, row=q*4+reg. Gate uniform per block
  // (n0 is 128-aligned, gate regions 1024-aligned).
  const int gate = n0 >> 10;
  f16* gp_out = (gate == 0) ? Zg : ((gate == 1) ? Fg : Og);
#pragma unroll
  for (int ni = 0; ni < 4; ++ni) {
    const int gcol = n0 + wn + ni * 16 + r;
    const int h = gcol & 1023;
    const float bv = bias[gcol];
#pragma unroll
    for (int mi = 0; mi < 4; ++mi) {
#pragma unroll
      for (int reg = 0; reg < 4; ++reg) {
        const int grow = m0 + wm + mi * 16 + q * 4 + reg;
        const int s = grow >> 4, bb = grow & 15;
        const float y = acc[mi][ni][reg] + bv;
        float v;
        if (gate == 0) v = 2.f / (1.f + __expf(-2.f * y)) - 1.f;  // tanh
        else           v = 1.f / (1.f + __expf(-y));              // sigmoid
        gp_out[(size_t)s * BH + bb * Hh + h] = (f16)v;
      }
    }
  }
}

// ---- sequence-parallel scan ------------------------------------------------
// Phase 1: per (chunk p, chain-pair q) compute A = prod(1-f), B = chunk scan
// from c=0. 16 x 8192 threads = 2048 waves (8/CU). f16x2 loads, U=16 dbuf.
__global__ __launch_bounds__(256, 4)
void chunk_reduce(const f16* __restrict__ Zg, const f16* __restrict__ Fg,
                  float* __restrict__ Apart, float* __restrict__ Bpart) {
  const int idx = blockIdx.x * 256 + threadIdx.x;
  const int q = idx & (NQ - 1);
  const int p = idx >> 13;
  const int base = p * CL;
  constexpr int U = 16;
  f16x2 zb[2][U], fb[2][U];
#pragma unroll
  for (int i = 0; i < U; ++i) {
    zb[0][i] = ((const f16x2*)(Zg + (size_t)(base + i) * BH))[q];
    fb[0][i] = ((const f16x2*)(Fg + (size_t)(base + i) * BH))[q];
  }
  float a0 = 1.f, a1 = 1.f, c0 = 0.f, c1 = 0.f;
  for (int t = 0; t < CL; t += 2 * U) {
#pragma unroll
    for (int i = 0; i < U; ++i) {
      zb[1][i] = ((const f16x2*)(Zg + (size_t)(base + t + U + i) * BH))[q];
      fb[1][i] = ((const f16x2*)(Fg + (size_t)(base + t + U + i) * BH))[q];
    }
#pragma unroll
    for (int i = 0; i < U; ++i) {
      const float f0 = (float)fb[0][i][0], f1 = (float)fb[0][i][1];
      const float z0 = (float)zb[0][i][0], z1 = (float)zb[0][i][1];
      c0 = fmaf(f0, z0 - c0, c0); c1 = fmaf(f1, z1 - c1, c1);
      a0 *= 1.f - f0; a1 *= 1.f - f1;
    }
    if (t + 2 * U < CL) {
#pragma unroll
      for (int i = 0; i < U; ++i) {
        zb[0][i] = ((const f16x2*)(Zg + (size_t)(base + t + 2 * U + i) * BH))[q];
        fb[0][i] = ((const f16x2*)(Fg + (size_t)(base + t + 2 * U + i) * BH))[q];
      }
    }
#pragma unroll
    for (int i = 0; i < U; ++i) {
      const float f0 = (float)fb[1][i][0], f1 = (float)fb[1][i][1];
      const float z0 = (float)zb[1][i][0], z1 = (float)zb[1][i][1];
      c0 = fmaf(f0, z0 - c0, c0); c1 = fmaf(f1, z1 - c1, c1);
      a0 *= 1.f - f0; a1 *= 1.f - f1;
    }
  }
  ((float2*)Apart)[(size_t)p * NQ + q] = make_float2(a0, a1);
  ((float2*)Bpart)[(size_t)p * NQ + q] = make_float2(c0, c1);
}

// Phase 2: scan the 16 chunk composites per chain; emit per-chunk entry state
// Cin[p] and c_last (= out's trailing BH floats).
__global__ __launch_bounds__(256)
void chunk_scan(const float* __restrict__ Apart, const float* __restrict__ Bpart,
                const float* __restrict__ hidden, float* __restrict__ Cin,
                float* __restrict__ out) {
  const int q = blockIdx.x * 256 + threadIdx.x;  // 0..NQ-1
  float2 c = ((const float2*)hidden)[q];
#pragma unroll
  for (int p = 0; p < NCH; ++p) {
    ((float2*)Cin)[(size_t)p * NQ + q] = c;
    const float2 a = ((const float2*)Apart)[(size_t)p * NQ + q];
    const float2 b = ((const float2*)Bpart)[(size_t)p * NQ + q];
    c.x = fmaf(a.x, c.x, b.x);
    c.y = fmaf(a.y, c.y, b.y);
  }
  ((float2*)(out + (size_t)Ss * BH))[q] = c;  // c_last
}

// Phase 3: replay each chunk from its entry state, apply output gate, store.
__global__ __launch_bounds__(256, 4)
void chunk_apply(const f16* __restrict__ Zg, const f16* __restrict__ Fg,
                 const f16* __restrict__ Og, const float* __restrict__ Cin,
                 float* __restrict__ out) {
  const int idx = blockIdx.x * 256 + threadIdx.x;
  const int q = idx & (NQ - 1);
  const int p = idx >> 13;
  const int base = p * CL;
  constexpr int U = 16;
  f16x2 zb[2][U], fb[2][U], ob[2][U];
#pragma unroll
  for (int i = 0; i < U; ++i) {
    zb[0][i] = ((const f16x2*)(Zg + (size_t)(base + i) * BH))[q];
    fb[0][i] = ((const f16x2*)(Fg + (size_t)(base + i) * BH))[q];
    ob[0][i] = ((const f16x2*)(Og + (size_t)(base + i) * BH))[q];
  }
  float2 c = ((const float2*)Cin)[(size_t)p * NQ + q];
  for (int t = 0; t < CL; t += 2 * U) {
#pragma unroll
    for (int i = 0; i < U; ++i) {
      zb[1][i] = ((const f16x2*)(Zg + (size_t)(base + t + U + i) * BH))[q];
      fb[1][i] = ((const f16x2*)(Fg + (size_t)(base + t + U + i) * BH))[q];
      ob[1][i] = ((const f16x2*)(Og + (size_t)(base + t + U + i) * BH))[q];
    }
#pragma unroll
    for (int i = 0; i < U; ++i) {
      const float f0 = (float)fb[0][i][0], f1 = (float)fb[0][i][1];
      const float z0 = (float)zb[0][i][0], z1 = (float)zb[0][i][1];
      c.x = fmaf(f0, z0 - c.x, c.x); c.y = fmaf(f1, z1 - c.y, c.y);
      ((float2*)(out + (size_t)(base + t + i) * BH))[q] =
          make_float2((float)ob[0][i][0] * c.x, (float)ob[0][i][1] * c.y);
    }
    if (t + 2 * U < CL) {
#pragma unroll
      for (int i = 0; i < U; ++i) {
        zb[0][i] = ((const f16x2*)(Zg + (size_t)(base + t + 2 * U + i) * BH))[q];
        fb[0][i] = ((const f16x2*)(Fg + (size_t)(base + t + 2 * U + i) * BH))[q];
        ob[0][i] = ((const f16x2*)(Og + (size_t)(base + t + 2 * U + i) * BH))[q];
      }
    }
#pragma unroll
    for (int i = 0; i < U; ++i) {
      const float f0 = (float)fb[1][i][0], f1 = (float)fb[1][i][1];
      const float z0 = (float)zb[1][i][0], z1 = (float)zb[1][i][1];
      c.x = fmaf(f0, z0 - c.x, c.x); c.y = fmaf(f1, z1 - c.y, c.y);
      ((float2*)(out + (size_t)(base + t + U + i) * BH))[q] =
          make_float2((float)ob[1][i][0] * c.x, (float)ob[1][i][1] * c.y);
    }
  }
}

extern "C" void kernel_launch(void* const* d_in, const int* in_sizes, int n_in,
                              void* d_out, int out_size, void* d_ws, size_t ws_size,
                              hipStream_t stream) {
  const float* X      = (const float*)d_in[0];  // (B,S,D)
  const float* hidden = (const float*)d_in[1];  // (B,H)
  const float* W      = (const float*)d_in[2];  // (3H,2D)
  const float* bias   = (const float*)d_in[3];  // (3H)
  float* out = (float*)d_out;

  // ws layout (all offsets 256B-aligned):
  //   [0,256)        zero block for s==0 shifted reads
  //   Wh  f16        12,582,912 B
  //   Xh  f16        67,108,864 B
  //   Zg/Fg/Og f16   67,108,864 B each
  //   Apart/Bpart/Cin fp32 16*16384*4 = 1,048,576 B each
  char* ws = (char*)d_ws;
  f16* zblk = (f16*)ws;
  f16* Wh = (f16*)(ws + 256);
  f16* Xh = (f16*)(ws + 256 + 12582912);
  f16* Zg = (f16*)(ws + 256 + 12582912 + 67108864);
  f16* Fg = (f16*)(ws + 256 + 12582912 + 2 * 67108864);
  f16* Og = (f16*)(ws + 256 + 12582912 + 3 * 67108864);
  float* Apart = (float*)(ws + 256 + 12582912 + 4 * 67108864);
  float* Bpart = Apart + NCH * BH;
  float* Cin   = Bpart + NCH * BH;

  hipMemsetAsync(zblk, 0, 256, stream);

  {
    int n4 = (Nn * Kk) / 4;
    cvt_f32_f16<<<(n4 + 255) / 256, 256, 0, stream>>>(W, Wh, n4);
  }
  {
    int n4 = (Bb * Ss * Dd) / 4;
    cvt_f32_f16<<<(n4 + 255) / 256, 256, 0, stream>>>(X, Xh, n4);
  }
  gemm_gates<<<dim3(24, 256), 256, 0, stream>>>(Xh, Wh, bias, zblk, Zg, Fg, Og);
  chunk_reduce<<<(NCH * NQ) / 256, 256, 0, stream>>>(Zg, Fg, Apart, Bpart);
  chunk_scan<<<NQ / 256, 256, 0, stream>>>(Apart, Bpart, hidden, Cin, out);
  chunk_apply<<<(NCH * NQ) / 256, 256, 0, stream>>>(Zg, Fg, Og, Cin, out);
}